// Round 4
// baseline (2954.824 us; speedup 1.0000x reference)
//
#include <hip/hip_runtime.h>
#include <hip/hip_fp16.h>
#include <stdint.h>

#define N_NODES 400000
#define N_EDGES 1600000
#define N_GRAPHS 10000
#define SLOPE 0.01f

typedef _Float16 hf4 __attribute__((ext_vector_type(4)));
typedef _Float16 hf8 __attribute__((ext_vector_type(8)));
typedef float f32x4 __attribute__((ext_vector_type(4)));

__device__ __forceinline__ float lrelu(float x) { return x > 0.f ? x : SLOPE * x; }

// ---------------------------------------------------------------------------
// Weight preprocessing (one 64-thread block):
//  bfold          = bi + be @ Wi_bot
//  WB0[j][40]     = fp16 (We@Wi_bot)[d][j]  (d<13; rest 0)      -- k_h0 B-slab
//  WLE[l][j][104] = fp16 [ Wl[l][k][j] (k<64) | (We@Wi_bot)[d][j] (d<13) | 0 ]
//  WTn[j][d]      = fp16 (Wn @ Wi_top)[d][j]  (d<74; 74..95 0)  bnWi = bn @ Wi_top
//  WTo[j][d]      = fp16 (Wn@Wa_top)[d][j] (d<74) | Wa_bot[d-80][j] (80<=d<144) | 0
//  bna            = ba + bn @ Wa_top
__global__ void k_fold(const float* We, const float* be, const float* Wi, const float* bi,
                       const float* Wn, const float* bn, const float* Wa, const float* ba,
                       const float* Wl, float* bfold, _Float16* WB0, _Float16* WLE,
                       _Float16* WTn, float* bnWi, _Float16* WTo, float* bna) {
    int j = threadIdx.x;  // 64 threads
    float wew[13];
    for (int d = 0; d < 13; d++) {
        float acc = 0.f;
        for (int k = 0; k < 64; k++) acc += We[d * 64 + k] * Wi[(64 + k) * 64 + j];
        wew[d] = acc;
    }
    float accb = bi[j];
    for (int k = 0; k < 64; k++) accb += be[k] * Wi[(64 + k) * 64 + j];
    bfold[j] = accb;
    for (int d = 0; d < 40; d++) WB0[j * 40 + d] = (_Float16)((d < 13) ? wew[d] : 0.f);
    for (int l = 0; l < 4; l++) {
        for (int k = 0; k < 64; k++)
            WLE[(l * 64 + j) * 104 + k] = (_Float16)Wl[l * 4096 + k * 64 + j];
        for (int d = 0; d < 40; d++)
            WLE[(l * 64 + j) * 104 + 64 + d] = (_Float16)((d < 13) ? wew[d] : 0.f);
    }
    for (int d = 0; d < 96; d++) {
        float acc = 0.f;
        if (d < 74)
            for (int k = 0; k < 64; k++) acc += Wn[d * 64 + k] * Wi[k * 64 + j];
        WTn[j * 96 + d] = (_Float16)acc;
    }
    {
        float acc = 0.f;
        for (int k = 0; k < 64; k++) acc += bn[k] * Wi[k * 64 + j];
        bnWi[j] = acc;
    }
    for (int d = 0; d < 160; d++) {
        float acc = 0.f;
        if (d < 74)
            for (int k = 0; k < 64; k++) acc += Wn[d * 64 + k] * Wa[k * 64 + j];
        else if (d >= 80 && d < 144)
            acc = Wa[(64 + d - 80) * 64 + j];
        WTo[j * 160 + d] = (_Float16)acc;
    }
    {
        float acc = ba[j];
        for (int k = 0; k < 64; k++) acc += bn[k] * Wa[k * 64 + j];
        bna[j] = acc;
    }
}

// ---------------------------------------------------------------------------
// nodeWi = nf @ WnWi + bnWi   (MFMA, fp16 out)
__global__ __launch_bounds__(256) void k_node(const float* nf, const _Float16* WTn,
                                              const float* bnWi, _Float16* nodeWi) {
    __shared__ __align__(16) _Float16 A[64 * 104];
    __shared__ __align__(16) _Float16 WT[64 * 104];
    int t = threadIdx.x;
    int n0 = blockIdx.x * 64;
    for (int idx = t; idx < 64 * 96; idx += 256) {
        int r = idx / 96, c = idx % 96;
        float v = (c < 74) ? nf[(size_t)(n0 + r) * 74 + c] : 0.f;
        A[r * 104 + c] = (_Float16)v;
    }
    for (int idx = t; idx < 64 * 24; idx += 256) {
        int r = idx / 24, c4 = idx % 24;
        *(hf4*)&WT[r * 104 + c4 * 4] = *(const hf4*)(WTn + r * 96 + c4 * 4);
    }
    __syncthreads();
    int lane = t & 63, w = t >> 6;
    int m16 = lane & 15, quad = lane >> 4;
    f32x4 acc[4];
#pragma unroll
    for (int jt = 0; jt < 4; jt++) acc[jt] = (f32x4){0.f, 0.f, 0.f, 0.f};
#pragma unroll
    for (int kt = 0; kt < 3; kt++) {
        hf8 a = *(const hf8*)&A[(w * 16 + m16) * 104 + kt * 32 + quad * 8];
#pragma unroll
        for (int jt = 0; jt < 4; jt++) {
            hf8 b = *(const hf8*)&WT[(jt * 16 + m16) * 104 + kt * 32 + quad * 8];
            acc[jt] = __builtin_amdgcn_mfma_f32_16x16x32_f16(a, b, acc[jt], 0, 0, 0);
        }
    }
#pragma unroll
    for (int jt = 0; jt < 4; jt++) {
        int col = jt * 16 + m16;
        float bb = bnWi[col];
#pragma unroll
        for (int r = 0; r < 4; r++) {
            int row = w * 16 + quad * 4 + r;
            nodeWi[(size_t)(n0 + row) * 64 + col] = (_Float16)(acc[jt][r] + bb);
        }
    }
}

// ---------------------------------------------------------------------------
// h = lrelu(nodeWi[src] + ef @ WeWi + bfold); fused scatter agg[dst] += h.
// ef@WeWi done by MFMA (K=32 slab, 13 real cols); epilogue in MFMA layout,
// nodeWi gathered per-thread (register-prefetched before the barrier).
// ONE barrier, no LDS round-trip.
__global__ __launch_bounds__(256) void k_h0(const float* ef, const int* src, const int* dst,
                                            const _Float16* WB0, const float* bfold,
                                            const _Float16* nodeWi, _Float16* h,
                                            __half2* agg2) {
    __shared__ __align__(16) _Float16 A[64 * 40];
    __shared__ __align__(16) _Float16 B[64 * 40];
    __shared__ int dstL[64];
    int t = threadIdx.x;
    int e0 = blockIdx.x * 64;
    int lane = t & 63, w = t >> 6, m16 = lane & 15, quad = lane >> 4;
    // prefetch nodeWi gather in MFMA-output layout (4 rows x 4 cols per thread)
    int rsrc[4];
#pragma unroll
    for (int r = 0; r < 4; r++) rsrc[r] = src[e0 + w * 16 + quad * 4 + r];
    _Float16 nwv[4][4];
#pragma unroll
    for (int r = 0; r < 4; r++)
#pragma unroll
        for (int jt = 0; jt < 4; jt++)
            nwv[r][jt] = nodeWi[(size_t)rsrc[r] * 64 + jt * 16 + m16];
    // stage B-slab (WeWiT fp16, 64x40)
    for (int idx = t; idx < 640; idx += 256) *(hf4*)&B[idx * 4] = *(const hf4*)(WB0 + idx * 4);
    // stage A-slab (ef fp16, 64x32 of stride 40; cols 13..31 zero)
#pragma unroll
    for (int i = 0; i < 2; i++) {
        int idx = t + 256 * i;
        int r = idx >> 3, c4 = idx & 7;
        hf4 m;
#pragma unroll
        for (int q = 0; q < 4; q++) {
            int d = c4 * 4 + q;
            m[q] = (_Float16)((d < 13) ? ef[(size_t)(e0 + r) * 13 + d] : 0.f);
        }
        *(hf4*)&A[r * 40 + c4 * 4] = m;
    }
    if (t < 64) dstL[t] = dst[e0 + t];
    float bfv[4];
#pragma unroll
    for (int jt = 0; jt < 4; jt++) bfv[jt] = bfold[jt * 16 + m16];
    __syncthreads();
    f32x4 acc[4];
#pragma unroll
    for (int jt = 0; jt < 4; jt++) acc[jt] = (f32x4){0.f, 0.f, 0.f, 0.f};
    hf8 a = *(const hf8*)&A[(w * 16 + m16) * 40 + quad * 8];
#pragma unroll
    for (int jt = 0; jt < 4; jt++) {
        hf8 b = *(const hf8*)&B[(jt * 16 + m16) * 40 + quad * 8];
        acc[jt] = __builtin_amdgcn_mfma_f32_16x16x32_f16(a, b, acc[jt], 0, 0, 0);
    }
#pragma unroll
    for (int r = 0; r < 4; r++) {
        int row = w * 16 + quad * 4 + r;
        int dn = dstL[row];
#pragma unroll
        for (int jt = 0; jt < 4; jt++) {
            int col = jt * 16 + m16;
            float z = acc[jt][r] + (float)nwv[r][jt] + bfv[jt];
            float v = lrelu(z);
            float vn = __shfl_down(v, 1, 64);
            if (!(m16 & 1)) {
                __half2 p = __halves2half2(__float2half(v), __float2half(vn));
                *(__half2*)&h[(size_t)(e0 + row) * 64 + col] = p;
                unsafeAtomicAdd(&agg2[(size_t)dn * 32 + (col >> 1)], p);
            }
        }
    }
}

// ---------------------------------------------------------------------------
// h = lrelu(h0 + (agg[src] - h[rev]) @ Wl + bl) in-place, fused scatter
// aggN[dst] += h_new.  h0 recomputed via a SECOND MFMA accumulator:
//   A = [ M (K=64) | ef16 (K=32 slab) ],  B = [ WlT | WeWiT ]  (WLE)
//   acc1 = M@Wl,  acc2 = ef@WeWi;  z = acc2 + nodeWi[src] + bfold
// Epilogue entirely in MFMA layout; ONE barrier; no Cs round-trip.
__global__ __launch_bounds__(256) void k_conv(const _Float16* agg, const _Float16* h_in,
                                              _Float16* h_out, const float* ef,
                                              const int* src, const int* dst,
                                              const _Float16* nodeWi, const _Float16* WLE,
                                              const float* bfold, const float* bl_g,
                                              int layer, __half2* aggN2) {
    __shared__ __align__(16) _Float16 A[64 * 104];
    __shared__ __align__(16) _Float16 Bs[64 * 104];
    __shared__ int dstL[64];
    int t = threadIdx.x;
    int e0 = blockIdx.x * 64;
    int lane = t & 63, w = t >> 6, m16 = lane & 15, quad = lane >> 4;
    const _Float16* Wg = WLE + (size_t)layer * 64 * 104;
    // prefetch nodeWi gather (MFMA layout) — latency hidden under staging+MFMA
    int rsrc[4];
#pragma unroll
    for (int r = 0; r < 4; r++) rsrc[r] = src[e0 + w * 16 + quad * 4 + r];
    _Float16 nwv[4][4];
#pragma unroll
    for (int r = 0; r < 4; r++)
#pragma unroll
        for (int jt = 0; jt < 4; jt++)
            nwv[r][jt] = nodeWi[(size_t)rsrc[r] * 64 + jt * 16 + m16];
    // stage B (WlT | WeWiT), 64x104 contiguous
    for (int idx = t; idx < 1664; idx += 256) *(hf4*)&Bs[idx * 4] = *(const hf4*)(Wg + idx * 4);
    // stage A cols 0..63: M = agg[src] - h_in[e^1]
#pragma unroll
    for (int i = 0; i < 4; i++) {
        int idx = t + 256 * i;
        int r = idx >> 4, c4 = idx & 15;
        int ge = e0 + r;
        int s = src[ge];
        hf4 av = *(const hf4*)(agg + (size_t)s * 64 + c4 * 4);
        hf4 hv = *(const hf4*)(h_in + (size_t)(ge ^ 1) * 64 + c4 * 4);
        hf4 m;
        m.x = av.x - hv.x; m.y = av.y - hv.y; m.z = av.z - hv.z; m.w = av.w - hv.w;
        *(hf4*)&A[r * 104 + c4 * 4] = m;
    }
    // stage A cols 64..95: ef fp16 (13 real + zeros)
#pragma unroll
    for (int i = 0; i < 2; i++) {
        int idx = t + 256 * i;
        int r = idx >> 3, c4 = idx & 7;
        hf4 m;
#pragma unroll
        for (int q = 0; q < 4; q++) {
            int d = c4 * 4 + q;
            m[q] = (_Float16)((d < 13) ? ef[(size_t)(e0 + r) * 13 + d] : 0.f);
        }
        *(hf4*)&A[r * 104 + 64 + c4 * 4] = m;
    }
    if (t < 64) dstL[t] = dst[e0 + t];
    float bfv[4], blv[4];
#pragma unroll
    for (int jt = 0; jt < 4; jt++) {
        bfv[jt] = bfold[jt * 16 + m16];
        blv[jt] = bl_g[layer * 64 + jt * 16 + m16];
    }
    __syncthreads();
    f32x4 acc1[4], acc2[4];
#pragma unroll
    for (int jt = 0; jt < 4; jt++) {
        acc1[jt] = (f32x4){0.f, 0.f, 0.f, 0.f};
        acc2[jt] = (f32x4){0.f, 0.f, 0.f, 0.f};
    }
    const int rowa = (w * 16 + m16) * 104;
#pragma unroll
    for (int kt = 0; kt < 2; kt++) {
        hf8 a = *(const hf8*)&A[rowa + kt * 32 + quad * 8];
#pragma unroll
        for (int jt = 0; jt < 4; jt++) {
            hf8 b = *(const hf8*)&Bs[(jt * 16 + m16) * 104 + kt * 32 + quad * 8];
            acc1[jt] = __builtin_amdgcn_mfma_f32_16x16x32_f16(a, b, acc1[jt], 0, 0, 0);
        }
    }
    {
        hf8 a = *(const hf8*)&A[rowa + 64 + quad * 8];
#pragma unroll
        for (int jt = 0; jt < 4; jt++) {
            hf8 b = *(const hf8*)&Bs[(jt * 16 + m16) * 104 + 64 + quad * 8];
            acc2[jt] = __builtin_amdgcn_mfma_f32_16x16x32_f16(a, b, acc2[jt], 0, 0, 0);
        }
    }
    // epilogue (MFMA layout): h0 = lrelu(acc2 + nw + bfold); val = lrelu(h0+acc1+bl)
#pragma unroll
    for (int r = 0; r < 4; r++) {
        int row = w * 16 + quad * 4 + r;
        int dn = dstL[row];
#pragma unroll
        for (int jt = 0; jt < 4; jt++) {
            int col = jt * 16 + m16;
            float z = acc2[jt][r] + (float)nwv[r][jt] + bfv[jt];
            float h0v = lrelu(z);
            float val = lrelu(h0v + acc1[jt][r] + blv[jt]);
            float vn = __shfl_down(val, 1, 64);
            if (!(m16 & 1)) {
                __half2 p = __halves2half2(__float2half(val), __float2half(vn));
                *(__half2*)&h_out[(size_t)(e0 + row) * 64 + col] = p;
                unsafeAtomicAdd(&aggN2[(size_t)dn * 32 + (col >> 1)], p);
            }
        }
    }
}

// ---------------------------------------------------------------------------
// z = nf @ Wna + agg @ Wab + bna (MFMA, K=160); g[gid] += lrelu(z)
// Segmented flush over sorted gid runs (one atomic burst per run).
__global__ __launch_bounds__(256) void k_nodeout(const float* nf, const _Float16* agg,
                                                 const _Float16* WTo, const float* bna,
                                                 const int* gidp, float* g) {
    __shared__ __align__(16) char uni[43008];
    _Float16* A = (_Float16*)uni;             // [64][168] fp16 (phase A/B)
    _Float16* WT = (_Float16*)(uni + 21504);  // [64][168] fp16 (phase A/B)
    float* Cs = (float*)uni;                  // [64][66] fp32 (phase C/D overlay)
    __shared__ int gidL[64];
    int t = threadIdx.x;
    int n0 = blockIdx.x * 64;
    for (int idx = t; idx < 64 * 80; idx += 256) {
        int r = idx / 80, c = idx % 80;
        float v = (c < 74) ? nf[(size_t)(n0 + r) * 74 + c] : 0.f;
        A[r * 168 + c] = (_Float16)v;
    }
    for (int idx = t; idx < 64 * 16; idx += 256) {
        int r = idx >> 4, c4 = idx & 15;
        *(hf4*)&A[r * 168 + 80 + c4 * 4] = *(const hf4*)(agg + (size_t)(n0 + r) * 64 + c4 * 4);
    }
    for (int idx = t; idx < 64 * 16; idx += 256) {
        int r = idx >> 4, c = idx & 15;
        A[r * 168 + 144 + c] = (_Float16)0.f;
    }
    for (int idx = t; idx < 64 * 40; idx += 256) {
        int r = idx / 40, c4 = idx % 40;
        *(hf4*)&WT[r * 168 + c4 * 4] = *(const hf4*)(WTo + r * 160 + c4 * 4);
    }
    if (t < 64) gidL[t] = gidp[n0 + t];
    __syncthreads();
    int lane = t & 63, w = t >> 6;
    int m16 = lane & 15, quad = lane >> 4;
    f32x4 acc[4];
#pragma unroll
    for (int jt = 0; jt < 4; jt++) acc[jt] = (f32x4){0.f, 0.f, 0.f, 0.f};
#pragma unroll
    for (int kt = 0; kt < 5; kt++) {
        hf8 a = *(const hf8*)&A[(w * 16 + m16) * 168 + kt * 32 + quad * 8];
#pragma unroll
        for (int jt = 0; jt < 4; jt++) {
            hf8 b = *(const hf8*)&WT[(jt * 16 + m16) * 168 + kt * 32 + quad * 8];
            acc[jt] = __builtin_amdgcn_mfma_f32_16x16x32_f16(a, b, acc[jt], 0, 0, 0);
        }
    }
    __syncthreads();
#pragma unroll
    for (int jt = 0; jt < 4; jt++) {
        int col = jt * 16 + m16;
        float bb = bna[col];
#pragma unroll
        for (int r = 0; r < 4; r++) {
            int row = w * 16 + quad * 4 + r;
            Cs[row * 66 + col] = lrelu(acc[jt][r] + bb);
        }
    }
    __syncthreads();
    int jj = t & 63, sub = t >> 6;
    int r0 = sub * 16;
    float run = Cs[r0 * 66 + jj];
    int curg = gidL[r0];
#pragma unroll
    for (int r = r0 + 1; r < r0 + 16; r++) {
        int gg = gidL[r];
        float v = Cs[r * 66 + jj];
        if (gg == curg) {
            run += v;
        } else {
            atomicAdd(&g[(size_t)curg * 64 + jj], run);
            curg = gg;
            run = v;
        }
    }
    atomicAdd(&g[(size_t)curg * 64 + jj], run);
}

// ---------------------------------------------------------------------------
// out = lrelu(g @ W1 + b1) @ W2 + b2   (one wave per graph)
__global__ __launch_bounds__(256) void k_head(const float* g, const float* W1,
                                              const float* b1, const float* W2,
                                              const float* b2, float* out) {
    __shared__ float W1L[4096];
    int t = threadIdx.x;
    for (int v = t; v < 4096; v += 256) W1L[v] = W1[v];
    __syncthreads();
    int w = t >> 6, j = t & 63;
    int graph = blockIdx.x * 4 + w;
    if (graph >= N_GRAPHS) return;
    const float* gr = g + (size_t)graph * 64;
    float acc = b1[j];
    for (int k = 0; k < 64; k++) acc += gr[k] * W1L[k * 64 + j];
    float p = lrelu(acc) * W2[j];
    for (int off = 32; off > 0; off >>= 1) p += __shfl_down(p, off, 64);
    if (j == 0) out[graph] = p + b2[0];
}

// ---------------------------------------------------------------------------
extern "C" void kernel_launch(void* const* d_in, const int* in_sizes, int n_in,
                              void* d_out, int out_size, void* d_ws, size_t ws_size,
                              hipStream_t stream) {
    const float* nf = (const float*)d_in[0];
    const float* ef = (const float*)d_in[1];
    const int* src = (const int*)d_in[2];
    const int* dst = (const int*)d_in[3];
    const int* gid = (const int*)d_in[4];
    const float* Wn = (const float*)d_in[5];
    const float* bn = (const float*)d_in[6];
    const float* We = (const float*)d_in[7];
    const float* be = (const float*)d_in[8];
    const float* Wi = (const float*)d_in[9];
    const float* bi = (const float*)d_in[10];
    const float* Wa = (const float*)d_in[11];
    const float* ba = (const float*)d_in[12];
    const float* Wl = (const float*)d_in[13];
    const float* bl = (const float*)d_in[14];
    const float* W1 = (const float*)d_in[15];
    const float* b1 = (const float*)d_in[16];
    const float* W2 = (const float*)d_in[17];
    const float* b2 = (const float*)d_in[18];

    char* ws = (char*)d_ws;
    size_t off = 0;
    auto alloc = [&](size_t bytes) -> char* {
        char* p = ws + off;
        off += (bytes + 255) & ~(size_t)255;
        return p;
    };
    // ~361.4 MB total (same footprint class as the verified round-1 layout)
    float* bfold = (float*)alloc(64 * 4);
    _Float16* WB0 = (_Float16*)alloc(64 * 40 * 2);
    _Float16* WLE = (_Float16*)alloc(4 * 64 * 104 * 2);
    _Float16* WTn = (_Float16*)alloc(64 * 96 * 2);
    float* bnWi = (float*)alloc(64 * 4);
    _Float16* WTo = (_Float16*)alloc(64 * 160 * 2);
    float* bna = (float*)alloc(64 * 4);
    _Float16* nodeWi = (_Float16*)alloc((size_t)N_NODES * 64 * 2);
    _Float16* h = (_Float16*)alloc((size_t)N_EDGES * 64 * 2);
    _Float16* aggA = (_Float16*)alloc((size_t)N_NODES * 64 * 2);
    _Float16* aggB = (_Float16*)alloc((size_t)N_NODES * 64 * 2);
    float* g = (float*)alloc((size_t)N_GRAPHS * 64 * 4);

    hipLaunchKernelGGL(k_fold, dim3(1), dim3(64), 0, stream, We, be, Wi, bi, Wn, bn, Wa, ba,
                       Wl, bfold, WB0, WLE, WTn, bnWi, WTo, bna);
    hipLaunchKernelGGL(k_node, dim3(N_NODES / 64), dim3(256), 0, stream, nf, WTn, bnWi, nodeWi);
    hipMemsetAsync(aggA, 0, (size_t)N_NODES * 64 * 2, stream);
    hipLaunchKernelGGL(k_h0, dim3(N_EDGES / 64), dim3(256), 0, stream, ef, src, dst, WB0,
                       bfold, nodeWi, h, (__half2*)aggA);

    _Float16* cur = aggA;
    _Float16* nxt = aggB;
    for (int l = 0; l < 4; l++) {
        hipMemsetAsync(nxt, 0, (size_t)N_NODES * 64 * 2, stream);
        hipLaunchKernelGGL(k_conv, dim3(N_EDGES / 64), dim3(256), 0, stream, cur, h, h, ef,
                           src, dst, nodeWi, WLE, bfold, bl, l, (__half2*)nxt);
        _Float16* tmp = cur; cur = nxt; nxt = tmp;
    }
    hipMemsetAsync(g, 0, (size_t)N_GRAPHS * 64 * 4, stream);
    hipLaunchKernelGGL(k_nodeout, dim3(N_NODES / 64), dim3(256), 0, stream, nf, cur, WTo, bna,
                       gid, g);
    hipLaunchKernelGGL(k_head, dim3(N_GRAPHS / 4), dim3(256), 0, stream, g, W1, b1, W2, b2,
                       (float*)d_out);
}

// Round 5
// 2389.455 us; speedup vs baseline: 1.2366x; 1.2366x over previous
//
#include <hip/hip_runtime.h>
#include <hip/hip_fp16.h>
#include <stdint.h>

#define N_NODES 400000
#define N_EDGES 1600000
#define N_GRAPHS 10000
#define SLOPE 0.01f

typedef _Float16 hf4 __attribute__((ext_vector_type(4)));
typedef _Float16 hf8 __attribute__((ext_vector_type(8)));
typedef float f32x4 __attribute__((ext_vector_type(4)));

__device__ __forceinline__ float lrelu(float x) { return x > 0.f ? x : SLOPE * x; }

// ---------------------------------------------------------------------------
// Weight preprocessing (one 64-thread block):
//  WeWi[13][64]   = We @ Wi_bot (fp32, for k_h0)   bfold = bi + be @ Wi_bot
//  WLE[l][j][104] = fp16 [ Wl[l][k][j] (k<64) | (We@Wi_bot)[d][j] (d<13) | 0 ]
//  WTn[j][d]      = fp16 (Wn @ Wi_top)[d][j]  (d<74; 74..95 0)  bnWi = bn @ Wi_top
//  WTo[j][d]      = fp16 (Wn@Wa_top)[d][j] (d<74) | Wa_bot[d-80][j] (80<=d<144) | 0
//  bna            = ba + bn @ Wa_top
__global__ void k_fold(const float* We, const float* be, const float* Wi, const float* bi,
                       const float* Wn, const float* bn, const float* Wa, const float* ba,
                       const float* Wl, float* WeWi, float* bfold, _Float16* WLE,
                       _Float16* WTn, float* bnWi, _Float16* WTo, float* bna) {
    int j = threadIdx.x;  // 64 threads
    float wew[13];
    for (int d = 0; d < 13; d++) {
        float acc = 0.f;
        for (int k = 0; k < 64; k++) acc += We[d * 64 + k] * Wi[(64 + k) * 64 + j];
        wew[d] = acc;
        WeWi[d * 64 + j] = acc;
    }
    float accb = bi[j];
    for (int k = 0; k < 64; k++) accb += be[k] * Wi[(64 + k) * 64 + j];
    bfold[j] = accb;
    for (int l = 0; l < 4; l++) {
        for (int k = 0; k < 64; k++)
            WLE[(l * 64 + j) * 104 + k] = (_Float16)Wl[l * 4096 + k * 64 + j];
        for (int d = 0; d < 40; d++)
            WLE[(l * 64 + j) * 104 + 64 + d] = (_Float16)((d < 13) ? wew[d] : 0.f);
    }
    for (int d = 0; d < 96; d++) {
        float acc = 0.f;
        if (d < 74)
            for (int k = 0; k < 64; k++) acc += Wn[d * 64 + k] * Wi[k * 64 + j];
        WTn[j * 96 + d] = (_Float16)acc;
    }
    {
        float acc = 0.f;
        for (int k = 0; k < 64; k++) acc += bn[k] * Wi[k * 64 + j];
        bnWi[j] = acc;
    }
    for (int d = 0; d < 160; d++) {
        float acc = 0.f;
        if (d < 74)
            for (int k = 0; k < 64; k++) acc += Wn[d * 64 + k] * Wa[k * 64 + j];
        else if (d >= 80 && d < 144)
            acc = Wa[(64 + d - 80) * 64 + j];
        WTo[j * 160 + d] = (_Float16)acc;
    }
    {
        float acc = ba[j];
        for (int k = 0; k < 64; k++) acc += bn[k] * Wa[k * 64 + j];
        bna[j] = acc;
    }
}

// ---------------------------------------------------------------------------
// nodeWi = nf @ WnWi + bnWi   (MFMA, fp16 out)
__global__ __launch_bounds__(256) void k_node(const float* nf, const _Float16* WTn,
                                              const float* bnWi, _Float16* nodeWi) {
    __shared__ __align__(16) _Float16 A[64 * 104];
    __shared__ __align__(16) _Float16 WT[64 * 104];
    int t = threadIdx.x;
    int n0 = blockIdx.x * 64;
    for (int idx = t; idx < 64 * 96; idx += 256) {
        int r = idx / 96, c = idx % 96;
        float v = (c < 74) ? nf[(size_t)(n0 + r) * 74 + c] : 0.f;
        A[r * 104 + c] = (_Float16)v;
    }
    for (int idx = t; idx < 64 * 24; idx += 256) {
        int r = idx / 24, c4 = idx % 24;
        *(hf4*)&WT[r * 104 + c4 * 4] = *(const hf4*)(WTn + r * 96 + c4 * 4);
    }
    __syncthreads();
    int lane = t & 63, w = t >> 6;
    int m16 = lane & 15, quad = lane >> 4;
    f32x4 acc[4];
#pragma unroll
    for (int jt = 0; jt < 4; jt++) acc[jt] = (f32x4){0.f, 0.f, 0.f, 0.f};
#pragma unroll
    for (int kt = 0; kt < 3; kt++) {
        hf8 a = *(const hf8*)&A[(w * 16 + m16) * 104 + kt * 32 + quad * 8];
#pragma unroll
        for (int jt = 0; jt < 4; jt++) {
            hf8 b = *(const hf8*)&WT[(jt * 16 + m16) * 104 + kt * 32 + quad * 8];
            acc[jt] = __builtin_amdgcn_mfma_f32_16x16x32_f16(a, b, acc[jt], 0, 0, 0);
        }
    }
#pragma unroll
    for (int jt = 0; jt < 4; jt++) {
        int col = jt * 16 + m16;
        float bb = bnWi[col];
#pragma unroll
        for (int r = 0; r < 4; r++) {
            int row = w * 16 + quad * 4 + r;
            nodeWi[(size_t)(n0 + row) * 64 + col] = (_Float16)(acc[jt][r] + bb);
        }
    }
}

// ---------------------------------------------------------------------------
// h = lrelu(nodeWi[src] + ef @ WeWi + bfold); fused scatter: agg[dst] += h
// (round-3 verified version: coalesced column-per-thread epilogue)
__global__ __launch_bounds__(256) void k_h0(const float* ef, const int* src, const int* dst,
                                            const float* WeWi, const float* bfold,
                                            const _Float16* nodeWi, _Float16* h0,
                                            __half2* agg2) {
    __shared__ float efL[832];
    __shared__ float WW[832];
    __shared__ float bf[64];
    __shared__ int dstL[64];
    int t = threadIdx.x;
    int e0 = blockIdx.x * 64;
    int j = t & 63, sub = t >> 6;
    int sv[16];
#pragma unroll
    for (int i = 0; i < 16; i++) sv[i] = src[e0 + sub + 4 * i];
    _Float16 nwv[16];
#pragma unroll
    for (int i = 0; i < 16; i++) nwv[i] = nodeWi[(size_t)sv[i] * 64 + j];
    for (int v = t; v < 832; v += 256) efL[v] = ef[(size_t)e0 * 13 + v];
    for (int v = t; v < 832; v += 256) WW[v] = WeWi[v];
    if (t < 64) { bf[t] = bfold[t]; dstL[t] = dst[e0 + t]; }
    __syncthreads();
    float bfj = bf[j];
#pragma unroll
    for (int i = 0; i < 16; i++) {
        int el = sub + 4 * i;
        int e = e0 + el;
        float acc = bfj + (float)nwv[i];
        const float* er = &efL[el * 13];
#pragma unroll
        for (int d = 0; d < 13; d++) acc += er[d] * WW[d * 64 + j];
        float v = lrelu(acc);
        h0[(size_t)e * 64 + j] = (_Float16)v;
        float vn = __shfl_down(v, 1, 64);
        if ((j & 1) == 0) {
            __half2 p = __halves2half2(__float2half(v), __float2half(vn));
            unsafeAtomicAdd(&agg2[(size_t)dstL[el] * 32 + (j >> 1)], p);
        }
    }
}

// ---------------------------------------------------------------------------
// h = lrelu(h0 + (agg[src] - h[rev]) @ Wl + bl) in-place, fused scatter
// aggN[dst] += h_new.  h0 recomputed via a SECOND MFMA accumulator
// (A = [M | ef16], B = WLE = [WlT | WeWiT]): acc1 = M@Wl, acc2 = ef@WeWi.
// BOTH accumulators round-trip through LDS (Cs1 fp32, Cs2 fp16) so the
// epilogue stays COLUMN-PER-THREAD: nodeWi gather / h store / agg atomic
// are all one 128B segment per instruction (round-4's MFMA-layout epilogue
// fragmented these 4x and regressed).
__global__ __launch_bounds__(256) void k_conv(const _Float16* agg, _Float16* h,
                                              const _Float16* nodeWi, const float* ef,
                                              const int* src, const int* dst,
                                              const _Float16* WLE, const float* bfold,
                                              const float* bl_g, int layer, __half2* aggN2) {
    __shared__ __align__(16) char uni[26880];
    _Float16* A = (_Float16*)uni;              // [64][104] fp16 (phase A/B)
    _Float16* Bs = (_Float16*)(uni + 13312);   // [64][104] fp16 (phase A/B)
    float* Cs1 = (float*)uni;                  // [64][66] fp32 (phase C/D overlay)
    _Float16* Cs2 = (_Float16*)(uni + 16896);  // [64][66] fp16 (phase C/D overlay)
    __shared__ int dstL[64];
    int t = threadIdx.x;
    int e0 = blockIdx.x * 64;
    int j = t & 63, sub = t >> 6;
    const _Float16* Wg = WLE + (size_t)layer * 64 * 104;
    // --- phase A: column-layout nodeWi prefetch (coalesced 128B rows);
    //     stage B = [WlT|WeWiT]; stage A = [M | ef16] ---
    int sv[16];
#pragma unroll
    for (int i = 0; i < 16; i++) sv[i] = src[e0 + sub + 4 * i];
    _Float16 nwv[16];
#pragma unroll
    for (int i = 0; i < 16; i++) nwv[i] = nodeWi[(size_t)sv[i] * 64 + j];
    for (int idx = t; idx < 1664; idx += 256)
        *(hf4*)&Bs[idx * 4] = *(const hf4*)(Wg + idx * 4);
#pragma unroll
    for (int i = 0; i < 4; i++) {
        int idx = t + 256 * i;  // 0..1023
        int r = idx >> 4, c4 = idx & 15;
        int ge = e0 + r;
        int s = src[ge];
        hf4 av = *(const hf4*)(agg + (size_t)s * 64 + c4 * 4);
        hf4 hv = *(const hf4*)(h + (size_t)(ge ^ 1) * 64 + c4 * 4);
        hf4 m;
        m.x = av.x - hv.x; m.y = av.y - hv.y; m.z = av.z - hv.z; m.w = av.w - hv.w;
        *(hf4*)&A[r * 104 + c4 * 4] = m;
    }
#pragma unroll
    for (int i = 0; i < 2; i++) {
        int idx = t + 256 * i;  // 0..511
        int r = idx >> 3, c4 = idx & 7;
        hf4 m;
#pragma unroll
        for (int q = 0; q < 4; q++) {
            int d = c4 * 4 + q;
            m[q] = (_Float16)((d < 13) ? ef[(size_t)(e0 + r) * 13 + d] : 0.f);
        }
        *(hf4*)&A[r * 104 + 64 + c4 * 4] = m;
    }
    if (t < 64) dstL[t] = dst[e0 + t];
    __syncthreads();
    // --- phase B: MFMA (12 total: 8 for M@Wl, 4 for ef@WeWi) ---
    int lane = t & 63, w = t >> 6;
    int m16 = lane & 15, quad = lane >> 4;
    f32x4 acc1[4], acc2[4];
#pragma unroll
    for (int jt = 0; jt < 4; jt++) {
        acc1[jt] = (f32x4){0.f, 0.f, 0.f, 0.f};
        acc2[jt] = (f32x4){0.f, 0.f, 0.f, 0.f};
    }
    const int rowa = (w * 16 + m16) * 104;
#pragma unroll
    for (int kt = 0; kt < 2; kt++) {
        hf8 a = *(const hf8*)&A[rowa + kt * 32 + quad * 8];
#pragma unroll
        for (int jt = 0; jt < 4; jt++) {
            hf8 b = *(const hf8*)&Bs[(jt * 16 + m16) * 104 + kt * 32 + quad * 8];
            acc1[jt] = __builtin_amdgcn_mfma_f32_16x16x32_f16(a, b, acc1[jt], 0, 0, 0);
        }
    }
    {
        hf8 a = *(const hf8*)&A[rowa + 64 + quad * 8];
#pragma unroll
        for (int jt = 0; jt < 4; jt++) {
            hf8 b = *(const hf8*)&Bs[(jt * 16 + m16) * 104 + 64 + quad * 8];
            acc2[jt] = __builtin_amdgcn_mfma_f32_16x16x32_f16(a, b, acc2[jt], 0, 0, 0);
        }
    }
    __syncthreads();
    // --- phase C: both accumulators -> LDS (stride 66: 2-way, free) ---
#pragma unroll
    for (int jt = 0; jt < 4; jt++)
#pragma unroll
        for (int r = 0; r < 4; r++) {
            int row = w * 16 + quad * 4 + r;
            int col = jt * 16 + m16;
            Cs1[row * 66 + col] = acc1[jt][r];
            Cs2[row * 66 + col] = (_Float16)acc2[jt][r];
        }
    __syncthreads();
    // --- phase D: column-per-thread epilogue + fused scatter (coalesced) ---
    float blj = bl_g[layer * 64 + j];
    float bfj = bfold[j];
#pragma unroll
    for (int i = 0; i < 16; i++) {
        int el = sub + 4 * i;
        int ge = e0 + el;
        float z = (float)Cs2[el * 66 + j] + (float)nwv[i] + bfj;
        float val = lrelu(lrelu(z) + Cs1[el * 66 + j] + blj);
        h[(size_t)ge * 64 + j] = (_Float16)val;
        float vn = __shfl_down(val, 1, 64);
        if ((j & 1) == 0) {
            __half2 p = __halves2half2(__float2half(val), __float2half(vn));
            unsafeAtomicAdd(&aggN2[(size_t)dstL[el] * 32 + (j >> 1)], p);
        }
    }
}

// ---------------------------------------------------------------------------
// z = nf @ Wna + agg @ Wab + bna (MFMA, K=160); g[gid] += lrelu(z)
// Segmented flush over sorted gid runs (one atomic burst per run).
__global__ __launch_bounds__(256) void k_nodeout(const float* nf, const _Float16* agg,
                                                 const _Float16* WTo, const float* bna,
                                                 const int* gidp, float* g) {
    __shared__ __align__(16) char uni[43008];
    _Float16* A = (_Float16*)uni;             // [64][168] fp16 (phase A/B)
    _Float16* WT = (_Float16*)(uni + 21504);  // [64][168] fp16 (phase A/B)
    float* Cs = (float*)uni;                  // [64][66] fp32 (phase C/D overlay)
    __shared__ int gidL[64];
    int t = threadIdx.x;
    int n0 = blockIdx.x * 64;
    for (int idx = t; idx < 64 * 80; idx += 256) {
        int r = idx / 80, c = idx % 80;
        float v = (c < 74) ? nf[(size_t)(n0 + r) * 74 + c] : 0.f;
        A[r * 168 + c] = (_Float16)v;
    }
    for (int idx = t; idx < 64 * 16; idx += 256) {
        int r = idx >> 4, c4 = idx & 15;
        *(hf4*)&A[r * 168 + 80 + c4 * 4] = *(const hf4*)(agg + (size_t)(n0 + r) * 64 + c4 * 4);
    }
    for (int idx = t; idx < 64 * 16; idx += 256) {
        int r = idx >> 4, c = idx & 15;
        A[r * 168 + 144 + c] = (_Float16)0.f;
    }
    for (int idx = t; idx < 64 * 40; idx += 256) {
        int r = idx / 40, c4 = idx % 40;
        *(hf4*)&WT[r * 168 + c4 * 4] = *(const hf4*)(WTo + r * 160 + c4 * 4);
    }
    if (t < 64) gidL[t] = gidp[n0 + t];
    __syncthreads();
    int lane = t & 63, w = t >> 6;
    int m16 = lane & 15, quad = lane >> 4;
    f32x4 acc[4];
#pragma unroll
    for (int jt = 0; jt < 4; jt++) acc[jt] = (f32x4){0.f, 0.f, 0.f, 0.f};
#pragma unroll
    for (int kt = 0; kt < 5; kt++) {
        hf8 a = *(const hf8*)&A[(w * 16 + m16) * 168 + kt * 32 + quad * 8];
#pragma unroll
        for (int jt = 0; jt < 4; jt++) {
            hf8 b = *(const hf8*)&WT[(jt * 16 + m16) * 168 + kt * 32 + quad * 8];
            acc[jt] = __builtin_amdgcn_mfma_f32_16x16x32_f16(a, b, acc[jt], 0, 0, 0);
        }
    }
    __syncthreads();
#pragma unroll
    for (int jt = 0; jt < 4; jt++) {
        int col = jt * 16 + m16;
        float bb = bna[col];
#pragma unroll
        for (int r = 0; r < 4; r++) {
            int row = w * 16 + quad * 4 + r;
            Cs[row * 66 + col] = lrelu(acc[jt][r] + bb);
        }
    }
    __syncthreads();
    int jj = t & 63, sub = t >> 6;
    int r0 = sub * 16;
    float run = Cs[r0 * 66 + jj];
    int curg = gidL[r0];
#pragma unroll
    for (int r = r0 + 1; r < r0 + 16; r++) {
        int gg = gidL[r];
        float v = Cs[r * 66 + jj];
        if (gg == curg) {
            run += v;
        } else {
            atomicAdd(&g[(size_t)curg * 64 + jj], run);
            curg = gg;
            run = v;
        }
    }
    atomicAdd(&g[(size_t)curg * 64 + jj], run);
}

// ---------------------------------------------------------------------------
// out = lrelu(g @ W1 + b1) @ W2 + b2   (one wave per graph)
__global__ __launch_bounds__(256) void k_head(const float* g, const float* W1,
                                              const float* b1, const float* W2,
                                              const float* b2, float* out) {
    __shared__ float W1L[4096];
    int t = threadIdx.x;
    for (int v = t; v < 4096; v += 256) W1L[v] = W1[v];
    __syncthreads();
    int w = t >> 6, j = t & 63;
    int graph = blockIdx.x * 4 + w;
    if (graph >= N_GRAPHS) return;
    const float* gr = g + (size_t)graph * 64;
    float acc = b1[j];
    for (int k = 0; k < 64; k++) acc += gr[k] * W1L[k * 64 + j];
    float p = lrelu(acc) * W2[j];
    for (int off = 32; off > 0; off >>= 1) p += __shfl_down(p, off, 64);
    if (j == 0) out[graph] = p + b2[0];
}

// ---------------------------------------------------------------------------
extern "C" void kernel_launch(void* const* d_in, const int* in_sizes, int n_in,
                              void* d_out, int out_size, void* d_ws, size_t ws_size,
                              hipStream_t stream) {
    const float* nf = (const float*)d_in[0];
    const float* ef = (const float*)d_in[1];
    const int* src = (const int*)d_in[2];
    const int* dst = (const int*)d_in[3];
    const int* gid = (const int*)d_in[4];
    const float* Wn = (const float*)d_in[5];
    const float* bn = (const float*)d_in[6];
    const float* We = (const float*)d_in[7];
    const float* be = (const float*)d_in[8];
    const float* Wi = (const float*)d_in[9];
    const float* bi = (const float*)d_in[10];
    const float* Wa = (const float*)d_in[11];
    const float* ba = (const float*)d_in[12];
    const float* Wl = (const float*)d_in[13];
    const float* bl = (const float*)d_in[14];
    const float* W1 = (const float*)d_in[15];
    const float* b1 = (const float*)d_in[16];
    const float* W2 = (const float*)d_in[17];
    const float* b2 = (const float*)d_in[18];

    char* ws = (char*)d_ws;
    size_t off = 0;
    auto alloc = [&](size_t bytes) -> char* {
        char* p = ws + off;
        off += (bytes + 255) & ~(size_t)255;
        return p;
    };
    // ~361 MB total (verified footprint class)
    float* WeWi = (float*)alloc(13 * 64 * 4);
    float* bfold = (float*)alloc(64 * 4);
    _Float16* WLE = (_Float16*)alloc(4 * 64 * 104 * 2);
    _Float16* WTn = (_Float16*)alloc(64 * 96 * 2);
    float* bnWi = (float*)alloc(64 * 4);
    _Float16* WTo = (_Float16*)alloc(64 * 160 * 2);
    float* bna = (float*)alloc(64 * 4);
    _Float16* nodeWi = (_Float16*)alloc((size_t)N_NODES * 64 * 2);
    _Float16* h = (_Float16*)alloc((size_t)N_EDGES * 64 * 2);
    _Float16* aggA = (_Float16*)alloc((size_t)N_NODES * 64 * 2);
    _Float16* aggB = (_Float16*)alloc((size_t)N_NODES * 64 * 2);
    float* g = (float*)alloc((size_t)N_GRAPHS * 64 * 4);

    hipLaunchKernelGGL(k_fold, dim3(1), dim3(64), 0, stream, We, be, Wi, bi, Wn, bn, Wa, ba,
                       Wl, WeWi, bfold, WLE, WTn, bnWi, WTo, bna);
    hipLaunchKernelGGL(k_node, dim3(N_NODES / 64), dim3(256), 0, stream, nf, WTn, bnWi, nodeWi);
    hipMemsetAsync(aggA, 0, (size_t)N_NODES * 64 * 2, stream);
    hipLaunchKernelGGL(k_h0, dim3(N_EDGES / 64), dim3(256), 0, stream, ef, src, dst, WeWi,
                       bfold, nodeWi, h, (__half2*)aggA);

    _Float16* cur = aggA;
    _Float16* nxt = aggB;
    for (int l = 0; l < 4; l++) {
        hipMemsetAsync(nxt, 0, (size_t)N_NODES * 64 * 2, stream);
        hipLaunchKernelGGL(k_conv, dim3(N_EDGES / 64), dim3(256), 0, stream, cur, h, nodeWi,
                           ef, src, dst, WLE, bfold, bl, l, (__half2*)nxt);
        _Float16* tmp = cur; cur = nxt; nxt = tmp;
    }
    hipMemsetAsync(g, 0, (size_t)N_GRAPHS * 64 * 4, stream);
    hipLaunchKernelGGL(k_nodeout, dim3(N_NODES / 64), dim3(256), 0, stream, nf, cur, WTo, bna,
                       gid, g);
    hipLaunchKernelGGL(k_head, dim3(N_GRAPHS / 4), dim3(256), 0, stream, g, W1, b1, W2, b2,
                       (float*)d_out);
}

// Round 6
// 2171.139 us; speedup vs baseline: 1.3610x; 1.1006x over previous
//
#include <hip/hip_runtime.h>
#include <hip/hip_fp16.h>
#include <stdint.h>

#define N_NODES 400000
#define N_EDGES 1600000
#define N_GRAPHS 10000
#define SLOPE 0.01f

typedef _Float16 hf4 __attribute__((ext_vector_type(4)));
typedef _Float16 hf8 __attribute__((ext_vector_type(8)));
typedef float f32x4 __attribute__((ext_vector_type(4)));

__device__ __forceinline__ float lrelu(float x) { return x > 0.f ? x : SLOPE * x; }

// ---------------------------------------------------------------------------
// Weight preprocessing (one 64-thread block):
//  WeWi[13][64]  = We @ Wi_bot          bfold = bi + be @ Wi_bot
//  WlT16[l][j][k] = fp16 Wl[l][k][j]
//  WTn[j][d]     = fp16 (Wn @ Wi_top)[d][j]   (d<74; 74..95 zero)   bnWi = bn @ Wi_top
//  WTo[j][d]     = fp16 (Wn @ Wa_top)[d][j] (d<74) | Wa_bot[d-80][j] (80<=d<144) | 0
//  bna           = ba + bn @ Wa_top
__global__ void k_fold(const float* We, const float* be, const float* Wi, const float* bi,
                       const float* Wn, const float* bn, const float* Wa, const float* ba,
                       const float* Wl, float* WeWi, float* bfold, _Float16* WlT16,
                       _Float16* WTn, float* bnWi, _Float16* WTo, float* bna) {
    int j = threadIdx.x;  // 64 threads
    for (int d = 0; d < 13; d++) {
        float acc = 0.f;
        for (int k = 0; k < 64; k++) acc += We[d * 64 + k] * Wi[(64 + k) * 64 + j];
        WeWi[d * 64 + j] = acc;
    }
    float accb = bi[j];
    for (int k = 0; k < 64; k++) accb += be[k] * Wi[(64 + k) * 64 + j];
    bfold[j] = accb;
    for (int l = 0; l < 4; l++)
        for (int k = 0; k < 64; k++)
            WlT16[l * 4096 + j * 64 + k] = (_Float16)Wl[l * 4096 + k * 64 + j];
    for (int d = 0; d < 96; d++) {
        float acc = 0.f;
        if (d < 74)
            for (int k = 0; k < 64; k++) acc += Wn[d * 64 + k] * Wi[k * 64 + j];
        WTn[j * 96 + d] = (_Float16)acc;
    }
    {
        float acc = 0.f;
        for (int k = 0; k < 64; k++) acc += bn[k] * Wi[k * 64 + j];
        bnWi[j] = acc;
    }
    for (int d = 0; d < 160; d++) {
        float acc = 0.f;
        if (d < 74)
            for (int k = 0; k < 64; k++) acc += Wn[d * 64 + k] * Wa[k * 64 + j];
        else if (d >= 80 && d < 144)
            acc = Wa[(64 + d - 80) * 64 + j];
        WTo[j * 160 + d] = (_Float16)acc;
    }
    {
        float acc = ba[j];
        for (int k = 0; k < 64; k++) acc += bn[k] * Wa[k * 64 + j];
        bna[j] = acc;
    }
}

// ---------------------------------------------------------------------------
// nodeWi = nf @ WnWi + bnWi   (MFMA, fp16 out)
__global__ __launch_bounds__(256) void k_node(const float* __restrict__ nf,
                                              const _Float16* __restrict__ WTn,
                                              const float* __restrict__ bnWi,
                                              _Float16* __restrict__ nodeWi) {
    __shared__ __align__(16) _Float16 A[64 * 104];
    __shared__ __align__(16) _Float16 WT[64 * 104];
    int t = threadIdx.x;
    int n0 = blockIdx.x * 64;
    for (int idx = t; idx < 64 * 96; idx += 256) {
        int r = idx / 96, c = idx % 96;
        float v = (c < 74) ? nf[(size_t)(n0 + r) * 74 + c] : 0.f;
        A[r * 104 + c] = (_Float16)v;
    }
    for (int idx = t; idx < 64 * 24; idx += 256) {
        int r = idx / 24, c4 = idx % 24;
        *(hf4*)&WT[r * 104 + c4 * 4] = *(const hf4*)(WTn + r * 96 + c4 * 4);
    }
    __syncthreads();
    int lane = t & 63, w = t >> 6;
    int m16 = lane & 15, quad = lane >> 4;
    f32x4 acc[4];
#pragma unroll
    for (int jt = 0; jt < 4; jt++) acc[jt] = (f32x4){0.f, 0.f, 0.f, 0.f};
#pragma unroll
    for (int kt = 0; kt < 3; kt++) {
        hf8 a = *(const hf8*)&A[(w * 16 + m16) * 104 + kt * 32 + quad * 8];
#pragma unroll
        for (int jt = 0; jt < 4; jt++) {
            hf8 b = *(const hf8*)&WT[(jt * 16 + m16) * 104 + kt * 32 + quad * 8];
            acc[jt] = __builtin_amdgcn_mfma_f32_16x16x32_f16(a, b, acc[jt], 0, 0, 0);
        }
    }
#pragma unroll
    for (int jt = 0; jt < 4; jt++) {
        int col = jt * 16 + m16;
        float bb = bnWi[col];
#pragma unroll
        for (int r = 0; r < 4; r++) {
            int row = w * 16 + quad * 4 + r;
            nodeWi[(size_t)(n0 + row) * 64 + col] = (_Float16)(acc[jt][r] + bb);
        }
    }
}

// ---------------------------------------------------------------------------
// h0 = lrelu(nodeWi[src] + ef @ WeWi + bfold); fused scatter: agg[dst] += h0.
// ZERO LDS / ZERO barriers: el = su*16+i is wave-uniform so ef/src/dst are
// scalar (s_load) operands; WW lives in 13 VGPRs; nodeWi gather coalesced.
__global__ __launch_bounds__(256, 8) void k_h0(const float* __restrict__ ef,
                                               const int* __restrict__ src,
                                               const int* __restrict__ dst,
                                               const float* __restrict__ WeWi,
                                               const float* __restrict__ bfold,
                                               const _Float16* __restrict__ nodeWi,
                                               _Float16* __restrict__ h0,
                                               __half2* __restrict__ agg2) {
    int t = threadIdx.x;
    int e0 = blockIdx.x * 64;
    int j = t & 63;
    int su = __builtin_amdgcn_readfirstlane(t >> 6);
    _Float16 nwv[16];
#pragma unroll
    for (int i = 0; i < 16; i++) {
        int s = src[e0 + su * 16 + i];  // uniform -> s_load
        nwv[i] = nodeWi[(size_t)s * 64 + j];
    }
    float wwv[13];
#pragma unroll
    for (int d = 0; d < 13; d++) wwv[d] = WeWi[d * 64 + j];
    float bfj = bfold[j];
#pragma unroll
    for (int i = 0; i < 16; i++) {
        int ge = e0 + su * 16 + i;
        const float* er = ef + (size_t)ge * 13;  // uniform -> s_load
        float z = bfj + (float)nwv[i];
#pragma unroll
        for (int d = 0; d < 13; d++) z += er[d] * wwv[d];
        float v = lrelu(z);
        h0[(size_t)ge * 64 + j] = (_Float16)v;
        float vn = __shfl_down(v, 1, 64);
        int dn = dst[ge];  // uniform -> s_load
        if ((j & 1) == 0) {
            __half2 p = __halves2half2(__float2half(v), __float2half(vn));
            unsafeAtomicAdd(&agg2[(size_t)dn * 32 + (j >> 1)], p);
        }
    }
}

// ---------------------------------------------------------------------------
// h = lrelu(h0 + (agg[src] - h[rev]) @ Wl + bl) in-place, fused scatter
// aggN[dst] += h_new, h0 recomputed (nodeWi[src] + ef@WeWi + bfold).
// vs round 3: ef/src/dst via scalar s_loads (wave-uniform el = su*16+i),
// WW in registers, no efL/WWL/bfL/dstL LDS -> LDS 25.6K->18.4K (8 blk/CU);
// accumulator round-trips LDS transposed via 4x ds_write_b128/ds_read_b128.
__global__ __launch_bounds__(256, 8) void k_conv(const _Float16* __restrict__ agg,
                                                 _Float16* __restrict__ h,
                                                 const _Float16* __restrict__ nodeWi,
                                                 const float* __restrict__ ef,
                                                 const int* __restrict__ src,
                                                 const int* __restrict__ dst,
                                                 const _Float16* __restrict__ WlT16,
                                                 const float* __restrict__ WeWi,
                                                 const float* __restrict__ bfold,
                                                 const float* __restrict__ bl_g, int layer,
                                                 __half2* __restrict__ aggN2) {
    __shared__ __align__(16) char uni[18432];
    _Float16* Msh = (_Float16*)uni;           // [64][72] fp16 (phase A/B)
    _Float16* WTs = (_Float16*)(uni + 9216);  // [64][72] fp16 (phase A/B)
    float* CsT = (float*)uni;                 // [64 cols][68] fp32 transposed (C/D)
    int t = threadIdx.x;
    int e0 = blockIdx.x * 64;
    int j = t & 63;
    int su = __builtin_amdgcn_readfirstlane(t >> 6);
    const _Float16* WTg = WlT16 + layer * 4096;
    // --- phase A: nodeWi prefetch (coalesced 128B rows, scalar src); stage WT, M ---
    _Float16 nwv[16];
#pragma unroll
    for (int i = 0; i < 16; i++) {
        int s = src[e0 + su * 16 + i];  // uniform -> s_load
        nwv[i] = nodeWi[(size_t)s * 64 + j];
    }
#pragma unroll
    for (int i = 0; i < 4; i++) {
        int idx = t + 256 * i;  // 0..1023
        int r = idx >> 4, c4 = idx & 15;
        *(hf4*)&WTs[r * 72 + c4 * 4] = *(const hf4*)(WTg + r * 64 + c4 * 4);
    }
#pragma unroll
    for (int i = 0; i < 4; i++) {
        int idx = t + 256 * i;
        int e = idx >> 4, k4 = idx & 15;
        int ge = e0 + e;
        int s = src[ge];
        hf4 av = *(const hf4*)(agg + (size_t)s * 64 + k4 * 4);
        hf4 hv = *(const hf4*)(h + (size_t)(ge ^ 1) * 64 + k4 * 4);
        hf4 m;
        m.x = av.x - hv.x; m.y = av.y - hv.y; m.z = av.z - hv.z; m.w = av.w - hv.w;
        *(hf4*)&Msh[e * 72 + k4 * 4] = m;
    }
    __syncthreads();
    // --- phase B: MFMA ---
    int lane = t & 63, w = t >> 6;
    int m16 = lane & 15, quad = lane >> 4;
    f32x4 acc[4];
#pragma unroll
    for (int jt = 0; jt < 4; jt++) acc[jt] = (f32x4){0.f, 0.f, 0.f, 0.f};
#pragma unroll
    for (int kt = 0; kt < 2; kt++) {
        hf8 a = *(const hf8*)&Msh[(w * 16 + m16) * 72 + kt * 32 + quad * 8];
#pragma unroll
        for (int jt = 0; jt < 4; jt++) {
            hf8 b = *(const hf8*)&WTs[(jt * 16 + m16) * 72 + kt * 32 + quad * 8];
            acc[jt] = __builtin_amdgcn_mfma_f32_16x16x32_f16(a, b, acc[jt], 0, 0, 0);
        }
    }
    __syncthreads();
    // --- phase C: acc -> LDS TRANSPOSED (CsT[col][row], stride 68 for 16B align);
    //     one ds_write_b128 per jt (rows quad*4..quad*4+3 contiguous) ---
#pragma unroll
    for (int jt = 0; jt < 4; jt++) {
        int col = jt * 16 + m16;
        *(f32x4*)&CsT[col * 68 + w * 16 + quad * 4] = acc[jt];
    }
    __syncthreads();
    // --- phase D: column-per-thread epilogue, 4x ds_read_b128 + scalar ef ---
    float wwv[13];
#pragma unroll
    for (int d = 0; d < 13; d++) wwv[d] = WeWi[d * 64 + j];
    float bfj = bfold[j];
    float blj = bl_g[layer * 64 + j];
#pragma unroll
    for (int c = 0; c < 4; c++) {
        f32x4 cs = *(const f32x4*)&CsT[j * 68 + su * 16 + c * 4];
#pragma unroll
        for (int r = 0; r < 4; r++) {
            int i = c * 4 + r;
            int ge = e0 + su * 16 + i;
            const float* er = ef + (size_t)ge * 13;  // uniform -> s_load
            float z = bfj + (float)nwv[i];
#pragma unroll
            for (int d = 0; d < 13; d++) z += er[d] * wwv[d];
            float val = lrelu(lrelu(z) + cs[r] + blj);
            h[(size_t)ge * 64 + j] = (_Float16)val;
            float vn = __shfl_down(val, 1, 64);
            int dn = dst[ge];  // uniform -> s_load
            if ((j & 1) == 0) {
                __half2 p = __halves2half2(__float2half(val), __float2half(vn));
                unsafeAtomicAdd(&aggN2[(size_t)dn * 32 + (j >> 1)], p);
            }
        }
    }
}

// ---------------------------------------------------------------------------
// z = nf @ Wna + agg @ Wab + bna (MFMA, K=160); g[gid] += lrelu(z)
// Segmented flush over sorted gid runs (one atomic burst per run).
__global__ __launch_bounds__(256) void k_nodeout(const float* __restrict__ nf,
                                                 const _Float16* __restrict__ agg,
                                                 const _Float16* __restrict__ WTo,
                                                 const float* __restrict__ bna,
                                                 const int* __restrict__ gidp,
                                                 float* __restrict__ g) {
    __shared__ __align__(16) char uni[43008];
    _Float16* A = (_Float16*)uni;             // [64][168] fp16 (phase A/B)
    _Float16* WT = (_Float16*)(uni + 21504);  // [64][168] fp16 (phase A/B)
    float* Cs = (float*)uni;                  // [64][66] fp32 (phase C/D overlay)
    __shared__ int gidL[64];
    int t = threadIdx.x;
    int n0 = blockIdx.x * 64;
    for (int idx = t; idx < 64 * 80; idx += 256) {
        int r = idx / 80, c = idx % 80;
        float v = (c < 74) ? nf[(size_t)(n0 + r) * 74 + c] : 0.f;
        A[r * 168 + c] = (_Float16)v;
    }
    for (int idx = t; idx < 64 * 16; idx += 256) {
        int r = idx >> 4, c4 = idx & 15;
        *(hf4*)&A[r * 168 + 80 + c4 * 4] = *(const hf4*)(agg + (size_t)(n0 + r) * 64 + c4 * 4);
    }
    for (int idx = t; idx < 64 * 16; idx += 256) {
        int r = idx >> 4, c = idx & 15;
        A[r * 168 + 144 + c] = (_Float16)0.f;
    }
    for (int idx = t; idx < 64 * 40; idx += 256) {
        int r = idx / 40, c4 = idx % 40;
        *(hf4*)&WT[r * 168 + c4 * 4] = *(const hf4*)(WTo + r * 160 + c4 * 4);
    }
    if (t < 64) gidL[t] = gidp[n0 + t];
    __syncthreads();
    int lane = t & 63, w = t >> 6;
    int m16 = lane & 15, quad = lane >> 4;
    f32x4 acc[4];
#pragma unroll
    for (int jt = 0; jt < 4; jt++) acc[jt] = (f32x4){0.f, 0.f, 0.f, 0.f};
#pragma unroll
    for (int kt = 0; kt < 5; kt++) {
        hf8 a = *(const hf8*)&A[(w * 16 + m16) * 168 + kt * 32 + quad * 8];
#pragma unroll
        for (int jt = 0; jt < 4; jt++) {
            hf8 b = *(const hf8*)&WT[(jt * 16 + m16) * 168 + kt * 32 + quad * 8];
            acc[jt] = __builtin_amdgcn_mfma_f32_16x16x32_f16(a, b, acc[jt], 0, 0, 0);
        }
    }
    __syncthreads();
#pragma unroll
    for (int jt = 0; jt < 4; jt++) {
        int col = jt * 16 + m16;
        float bb = bna[col];
#pragma unroll
        for (int r = 0; r < 4; r++) {
            int row = w * 16 + quad * 4 + r;
            Cs[row * 66 + col] = lrelu(acc[jt][r] + bb);
        }
    }
    __syncthreads();
    int jj = t & 63, sub = t >> 6;
    int r0 = sub * 16;
    float run = Cs[r0 * 66 + jj];
    int curg = gidL[r0];
#pragma unroll
    for (int r = r0 + 1; r < r0 + 16; r++) {
        int gg = gidL[r];
        float v = Cs[r * 66 + jj];
        if (gg == curg) {
            run += v;
        } else {
            atomicAdd(&g[(size_t)curg * 64 + jj], run);
            curg = gg;
            run = v;
        }
    }
    atomicAdd(&g[(size_t)curg * 64 + jj], run);
}

// ---------------------------------------------------------------------------
// out = lrelu(g @ W1 + b1) @ W2 + b2   (one wave per graph)
__global__ __launch_bounds__(256) void k_head(const float* __restrict__ g,
                                              const float* __restrict__ W1,
                                              const float* __restrict__ b1,
                                              const float* __restrict__ W2,
                                              const float* __restrict__ b2,
                                              float* __restrict__ out) {
    __shared__ float W1L[4096];
    int t = threadIdx.x;
    for (int v = t; v < 4096; v += 256) W1L[v] = W1[v];
    __syncthreads();
    int w = t >> 6, j = t & 63;
    int graph = blockIdx.x * 4 + w;
    if (graph >= N_GRAPHS) return;
    const float* gr = g + (size_t)graph * 64;
    float acc = b1[j];
    for (int k = 0; k < 64; k++) acc += gr[k] * W1L[k * 64 + j];
    float p = lrelu(acc) * W2[j];
    for (int off = 32; off > 0; off >>= 1) p += __shfl_down(p, off, 64);
    if (j == 0) out[graph] = p + b2[0];
}

// ---------------------------------------------------------------------------
extern "C" void kernel_launch(void* const* d_in, const int* in_sizes, int n_in,
                              void* d_out, int out_size, void* d_ws, size_t ws_size,
                              hipStream_t stream) {
    const float* nf = (const float*)d_in[0];
    const float* ef = (const float*)d_in[1];
    const int* src = (const int*)d_in[2];
    const int* dst = (const int*)d_in[3];
    const int* gid = (const int*)d_in[4];
    const float* Wn = (const float*)d_in[5];
    const float* bn = (const float*)d_in[6];
    const float* We = (const float*)d_in[7];
    const float* be = (const float*)d_in[8];
    const float* Wi = (const float*)d_in[9];
    const float* bi = (const float*)d_in[10];
    const float* Wa = (const float*)d_in[11];
    const float* ba = (const float*)d_in[12];
    const float* Wl = (const float*)d_in[13];
    const float* bl = (const float*)d_in[14];
    const float* W1 = (const float*)d_in[15];
    const float* b1 = (const float*)d_in[16];
    const float* W2 = (const float*)d_in[17];
    const float* b2 = (const float*)d_in[18];

    char* ws = (char*)d_ws;
    size_t off = 0;
    auto alloc = [&](size_t bytes) -> char* {
        char* p = ws + off;
        off += (bytes + 255) & ~(size_t)255;
        return p;
    };
    // ~361 MB total (verified footprint)
    float* WeWi = (float*)alloc(13 * 64 * 4);
    float* bfold = (float*)alloc(64 * 4);
    _Float16* WlT16 = (_Float16*)alloc(4 * 4096 * 2);
    _Float16* WTn = (_Float16*)alloc(64 * 96 * 2);
    float* bnWi = (float*)alloc(64 * 4);
    _Float16* WTo = (_Float16*)alloc(64 * 160 * 2);
    float* bna = (float*)alloc(64 * 4);
    _Float16* nodeWi = (_Float16*)alloc((size_t)N_NODES * 64 * 2);
    _Float16* h = (_Float16*)alloc((size_t)N_EDGES * 64 * 2);
    _Float16* aggA = (_Float16*)alloc((size_t)N_NODES * 64 * 2);
    _Float16* aggB = (_Float16*)alloc((size_t)N_NODES * 64 * 2);
    float* g = (float*)alloc((size_t)N_GRAPHS * 64 * 4);

    hipLaunchKernelGGL(k_fold, dim3(1), dim3(64), 0, stream, We, be, Wi, bi, Wn, bn, Wa, ba,
                       Wl, WeWi, bfold, WlT16, WTn, bnWi, WTo, bna);
    hipLaunchKernelGGL(k_node, dim3(N_NODES / 64), dim3(256), 0, stream, nf, WTn, bnWi, nodeWi);
    hipMemsetAsync(aggA, 0, (size_t)N_NODES * 64 * 2, stream);
    hipLaunchKernelGGL(k_h0, dim3(N_EDGES / 64), dim3(256), 0, stream, ef, src, dst, WeWi,
                       bfold, nodeWi, h, (__half2*)aggA);

    _Float16* cur = aggA;
    _Float16* nxt = aggB;
    for (int l = 0; l < 4; l++) {
        hipMemsetAsync(nxt, 0, (size_t)N_NODES * 64 * 2, stream);
        hipLaunchKernelGGL(k_conv, dim3(N_EDGES / 64), dim3(256), 0, stream, cur, h, nodeWi,
                           ef, src, dst, WlT16, WeWi, bfold, bl, l, (__half2*)nxt);
        _Float16* tmp = cur; cur = nxt; nxt = tmp;
    }
    hipMemsetAsync(g, 0, (size_t)N_GRAPHS * 64 * 4, stream);
    hipLaunchKernelGGL(k_nodeout, dim3(N_NODES / 64), dim3(256), 0, stream, nf, cur, WTo, bna,
                       gid, g);
    hipLaunchKernelGGL(k_head, dim3(N_GRAPHS / 4), dim3(256), 0, stream, g, W1, b1, W2, b2,
                       (float*)d_out);
}